// Round 11
// baseline (63.745 us; speedup 1.0000x reference)
//
#include <hip/hip_runtime.h>
#include <hip/hip_bf16.h>
#include <math.h>

#define HH 128
#define WW 128
#define HW 16384
#define BATCH 8

// 2D tile geometry (fused kernel)
#define TR 8            // tile rows per block
#define TC 16           // tile cols per block
#define HALO 2
#define PR 12           // TR + 2*HALO
#define PC 20           // TC + 2*HALO
#define PST 36          // dwords per patch pixel (32 data + 4 pad)

typedef __attribute__((ext_vector_type(8))) short short8;
typedef __attribute__((ext_vector_type(16))) float f32x16;
typedef __attribute__((ext_vector_type(4))) unsigned int u32x4;
typedef __attribute__((ext_vector_type(2))) float f32x2;

union FragU { short8 v; unsigned int u[4]; u32x4 q; };

static __device__ __forceinline__ unsigned short f2bf(float f) {
    __hip_bfloat16 h = __float2bfloat16(f);
    return *(unsigned short*)&h;
}
// unpack a bf16 channel-pair into {even, odd} as f32x2
static __device__ __forceinline__ f32x2 upk2(unsigned int r) {
    f32x2 v;
    v.x = __uint_as_float(r << 16);
    v.y = __uint_as_float(r & 0xffff0000u);
    return v;
}
// packed-f32 bilerp: 4x v_pk_fma_f32 per channel-pair instead of 8 scalar FMA
static __device__ __forceinline__ short8 bilerp_frag(
    u32x4 r00, u32x4 r01, u32x4 r10, u32x4 r11,
    float w0, float w1, float w2, float w3)
{
    FragU bf;
    f32x2 W0 = {w0, w0}, W1 = {w1, w1}, W2 = {w2, w2}, W3 = {w3, w3};
#pragma unroll
    for (int d = 0; d < 4; ++d) {
        f32x2 s = upk2(r00[d]) * W0;
        s = __builtin_elementwise_fma(upk2(r01[d]), W1, s);
        s = __builtin_elementwise_fma(upk2(r10[d]), W2, s);
        s = __builtin_elementwise_fma(upk2(r11[d]), W3, s);
        float2 f2; f2.x = s.x; f2.y = s.y;
        __hip_bfloat162 h2 = __float22bfloat162_rn(f2);
        bf.u[d] = *(unsigned int*)&h2;
    }
    return bf.v;
}

// register index inside f32x16 acc holding D-row `row` (32x32 layout):
// row = (r&3) + 8*(r>>2) + 4*hi  =>  r = (row&3) | ((row>>3)<<2), lane += 32*((row>>2)&1)
#define RR(row) (((row) & 3) | (((row) >> 3) << 2))
#define HB(row) ((((row) >> 2) & 1) << 5)

// ---------------------------------------------------------------------------
// Prep: pack weights for 32x32x16 MFMA A-operand, bf16 (verified r8).
// A lane l: row = l&31, k-elems j=0..7 -> channel c = s*16 + 8*(l>>5) + j
//   wA : (m=2, kk=9, s=4, lane=64, j=8) bf16   <- weight (64,64,3,3)
//   owA: (kk=9, s=4, lane=64, j=8)      bf16   <- offset_w (27,64,3,3)
// ---------------------------------------------------------------------------
__global__ __launch_bounds__(256) void prep_kernel(
    const float* __restrict__ weight,
    const float* __restrict__ offset_w,
    unsigned short* __restrict__ wA,
    unsigned short* __restrict__ owA)
{
    int id = blockIdx.x * 256 + threadIdx.x;
    if (id < 4608) {                        // 2*9*4*64
        int m = id / 2304;
        int rem = id % 2304;
        int kk = rem >> 8;
        int s = (rem >> 6) & 3;
        int l = id & 63;
        int cout = m * 32 + (l & 31);
        int cbase = s * 16 + 8 * (l >> 5);
#pragma unroll
        for (int j = 0; j < 8; ++j) {
            wA[id * 8 + j] = f2bf(weight[(cout * 64 + cbase + j) * 9 + kk]);
        }
        return;
    }
    int id2 = id - 4608;
    if (id2 < 2304) {                       // 9*4*64
        int kk = id2 >> 8;
        int s = (id2 >> 6) & 3;
        int l = id2 & 63;
        int cout = l & 31;
        int cbase = s * 16 + 8 * (l >> 5);
#pragma unroll
        for (int j = 0; j < 8; ++j) {
            float v = (cout < 27) ? offset_w[(cout * 64 + cbase + j) * 9 + kk] : 0.0f;
            owA[id2 * 8 + j] = f2bf(v);
        }
    }
}

// ---------------------------------------------------------------------------
// Transform: x NCHW fp32 -> xT NHWC bf16 (u32 channel-pairs), LDS-tiled.
// ---------------------------------------------------------------------------
__global__ __launch_bounds__(256) void transform_kernel(
    const float* __restrict__ x,
    unsigned int* __restrict__ xT)
{
    __shared__ unsigned int lds[64][33];
    int bid = blockIdx.x;
    int b = bid & 7;                        // image -> XCD
    int pix0 = (bid >> 3) << 6;
    int t = threadIdx.x;
    int px = t & 63;
    int cp0 = (t >> 6) * 8;

    const float* xb = x + (size_t)b * 64 * HW + pix0 + px;
#pragma unroll
    for (int it = 0; it < 8; ++it) {
        int cpair = cp0 + it;
        float2 f2;
        f2.x = xb[(size_t)(2 * cpair) * HW];
        f2.y = xb[(size_t)(2 * cpair + 1) * HW];
        __hip_bfloat162 h2 = __float22bfloat162_rn(f2);
        lds[px][cpair] = *(unsigned int*)&h2;
    }
    __syncthreads();

    int wpx = t >> 2, qq = t & 3;
    unsigned int* dst = xT + ((size_t)b * HW + pix0 + wpx) * 32 + qq * 8;
    u32x4 a, c;
#pragma unroll
    for (int j = 0; j < 4; ++j) a[j] = lds[wpx][qq * 8 + j];
#pragma unroll
    for (int j = 0; j < 4; ++j) c[j] = lds[wpx][qq * 8 + 4 + j];
    *(u32x4*)dst = a;
    *(u32x4*)(dst + 4) = c;
}

// ---------------------------------------------------------------------------
// Fused kernel, LDS-patch v3.
//   vs r10: (a) `red` LDS array eliminated -- phase-1 acc1 stays in registers
//   and phase 2 reads dy/dx/mask via __shfl with compile-time register index
//   (phase-2 kk loop fully unrolled); LDS = patch only (34.56KB) -> 4
//   blocks/CU, grid = exactly 4/CU -> no scheduling tail.
//   (b) bilerp on packed f32x2 (v_pk_fma_f32) -> ~25% fewer VALU instrs.
//   __launch_bounds__(256,4): ~128-reg budget; live set ~110 (A-frags JIT,
//   corners consumed immediately). Spill sentinel: FETCH_SIZE.
// ---------------------------------------------------------------------------
__global__ __launch_bounds__(256, 4) void fused_kernel(
    const unsigned int* __restrict__ xT,    // NHWC bf16
    const unsigned short* __restrict__ wA,  // (2,9,4,64,8) bf16
    const unsigned short* __restrict__ owA, // (9,4,64,8) bf16
    const float* __restrict__ bias,         // (64,)
    const float* __restrict__ offset_b,     // (27,)
    float* __restrict__ out)                // (B,64,HW) f32
{
    __shared__ unsigned int patch[PR * PC * PST];   // 34.56 KB (only LDS)

    int t = threadIdx.x;
    int lane = t & 63;
    int wid = t >> 6;
    int bid = blockIdx.x;
    int b = bid & 7;                        // image -> XCD
    int tile = bid >> 3;                    // 0..127
    int ho0 = (tile >> 3) * TR;
    int wo0 = (tile & 7) * TC;
    int py0 = ho0 - HALO;
    int px0 = wo0 - HALO;

    int q = lane & 31;                      // pixel within wave
    int hi = lane >> 5;                     // channel-half
    int ho = ho0 + 2 * wid + (q >> 4);
    int wo = wo0 + (q & 15);
    int p = ho * WW + wo;

    const unsigned int* xb = xT + (size_t)b * HW * 32;
    const short8* wAv = (const short8*)wA;
    const short8* owAv = (const short8*)owA;

    // ---------------- stage patch (coalesced, clamped) ----------------
#pragma unroll
    for (int it = 0; it < 8; ++it) {
        int id = it * 256 + t;
        if (id < PR * PC * 8) {             // 1920 16B-chunks
            int row = id / (PC * 8);
            int rem = id - row * (PC * 8);
            int col = rem >> 3;
            int c = rem & 7;
            int yc = min(max(py0 + row, 0), HH - 1);
            int xc = min(max(px0 + col, 0), WW - 1);
            u32x4 v = *(const u32x4*)(xb + (size_t)(yc * WW + xc) * 32 + c * 4);
            *(u32x4*)&patch[(row * PC + col) * PST + c * 4] = v;
        }
    }
    __syncthreads();                        // the ONLY barrier

    // ---------------- phase 1: offset conv (result stays in registers) ----
    f32x16 acc1 = {};
#pragma unroll
    for (int kk = 0; kk < 9; ++kk) {
        int iy = ho + kk / 3 - 1;
        int ix = wo + kk % 3 - 1;
        bool ok = ((unsigned)iy < 128u) && ((unsigned)ix < 128u);
        int jy = min(max(iy, 0), 127) - py0;
        int jx = min(max(ix, 0), 127) - px0;
        int base = (jy * PC + jx) * PST + (hi << 2);
#pragma unroll
        for (int s = 0; s < 4; ++s) {
            u32x4 raw = *(const u32x4*)&patch[base + s * 8];
            FragU bf;
#pragma unroll
            for (int j = 0; j < 4; ++j) bf.u[j] = ok ? raw[j] : 0u;
            acc1 = __builtin_amdgcn_mfma_f32_32x32x16_bf16(
                owAv[(kk * 4 + s) * 64 + lane], bf.v, acc1, 0, 0, 0);
        }
    }
    // bias + sigmoid in place (compile-time indices)
#pragma unroll
    for (int r = 0; r < 16; ++r) {
        int cout = (r & 3) + 8 * (r >> 2) + 4 * hi;
        if (cout < 27) {
            float a = acc1[r] + offset_b[cout];
            if (cout >= 18) a = 1.0f / (1.0f + __expf(-a));
            acc1[r] = a;
        }
    }

    // ---------------- phase 2: deformable conv ----------------
    f32x16 acc[2];
#pragma unroll
    for (int m = 0; m < 2; ++m) {
#pragma unroll
        for (int r = 0; r < 16; ++r) {
            acc[m][r] = bias[m * 32 + (r & 3) + 8 * (r >> 2) + 4 * hi];
        }
    }

#pragma unroll
    for (int kk = 0; kk < 9; ++kk) {
        // dy,dx,mask for this lane's pixel via cross-lane register read
        // (RR/HB are compile-time since kk is unrolled)
        float dy = __shfl(acc1[RR(2 * kk)],     q + HB(2 * kk));
        float dx = __shfl(acc1[RR(2 * kk + 1)], q + HB(2 * kk + 1));
        float mm = __shfl(acc1[RR(18 + kk)],    q + HB(18 + kk));

        float py = dy + (float)(kk / 3 + ho - 1);
        float px = dx + (float)(kk % 3 + wo - 1);
        float y0f = floorf(py), x0f = floorf(px);
        float wy = py - y0f, wx = px - x0f;
        int y0 = (int)y0f, x0 = (int)x0f;
        int y1 = y0 + 1, x1 = x0 + 1;
        bool y0ok = (unsigned)y0 < 128u, y1ok = (unsigned)y1 < 128u;
        bool x0ok = (unsigned)x0 < 128u, x1ok = (unsigned)x1 < 128u;
        float w0 = (y0ok && x0ok) ? (1.0f - wy) * (1.0f - wx) * mm : 0.0f;
        float w1 = (y0ok && x1ok) ? (1.0f - wy) * wx * mm : 0.0f;
        float w2 = (y1ok && x0ok) ? wy * (1.0f - wx) * mm : 0.0f;
        float w3 = (y1ok && x1ok) ? wy * wx * mm : 0.0f;
        int y0c = min(max(y0, 0), 127), y1c = min(max(y1, 0), 127);
        int x0c = min(max(x0, 0), 127), x1c = min(max(x1, 0), 127);

        int jy0 = y0c - py0, jy1 = y1c - py0;
        int jx0 = x0c - px0, jx1 = x1c - px0;
        bool inp = ((unsigned)jy0 < (unsigned)PR) && ((unsigned)jy1 < (unsigned)PR) &&
                   ((unsigned)jx0 < (unsigned)PC) && ((unsigned)jx1 < (unsigned)PC);

        // A-frags loaded just-in-time inside each step: only 2 live at once.
#define P2_STEP(S, R00, R01, R10, R11) {                                    \
            short8 A0 = wAv[(kk * 4 + (S)) * 64 + lane];                    \
            short8 A1 = wAv[(36 + kk * 4 + (S)) * 64 + lane];               \
            short8 bf = bilerp_frag(R00, R01, R10, R11, w0, w1, w2, w3);    \
            acc[0] = __builtin_amdgcn_mfma_f32_32x32x16_bf16(A0, bf, acc[0], 0, 0, 0); \
            acc[1] = __builtin_amdgcn_mfma_f32_32x32x16_bf16(A1, bf, acc[1], 0, 0, 0); \
        }

        if (__all(inp)) {
            int b00 = (jy0 * PC + jx0) * PST + (hi << 2);
            int b01 = (jy0 * PC + jx1) * PST + (hi << 2);
            int b10 = (jy1 * PC + jx0) * PST + (hi << 2);
            int b11 = (jy1 * PC + jx1) * PST + (hi << 2);
#define LRD(B, S) (*(const u32x4*)&patch[(B) + (S) * 8])
            P2_STEP(0, LRD(b00,0), LRD(b01,0), LRD(b10,0), LRD(b11,0));
            P2_STEP(1, LRD(b00,1), LRD(b01,1), LRD(b10,1), LRD(b11,1));
            P2_STEP(2, LRD(b00,2), LRD(b01,2), LRD(b10,2), LRD(b11,2));
            P2_STEP(3, LRD(b00,3), LRD(b01,3), LRD(b10,3), LRD(b11,3));
#undef LRD
        } else {
            int o00 = (y0c * WW + x0c) * 32 + (hi << 2);
            int o01 = (y0c * WW + x1c) * 32 + (hi << 2);
            int o10 = (y1c * WW + x0c) * 32 + (hi << 2);
            int o11 = (y1c * WW + x1c) * 32 + (hi << 2);
#define GRD(O, S) (*(const u32x4*)(xb + (O) + (S) * 8))
            P2_STEP(0, GRD(o00,0), GRD(o01,0), GRD(o10,0), GRD(o11,0));
            P2_STEP(1, GRD(o00,1), GRD(o01,1), GRD(o10,1), GRD(o11,1));
            P2_STEP(2, GRD(o00,2), GRD(o01,2), GRD(o10,2), GRD(o11,2));
            P2_STEP(3, GRD(o00,3), GRD(o01,3), GRD(o10,3), GRD(o11,3));
#undef GRD
        }
#undef P2_STEP
    }

    // D: row(cout) = m*32 + (r&3)+8*(r>>2)+4*hi, col(pixel) = q
#pragma unroll
    for (int m = 0; m < 2; ++m) {
#pragma unroll
        for (int r = 0; r < 16; ++r) {
            int cout = m * 32 + (r & 3) + 8 * (r >> 2) + 4 * hi;
            out[((size_t)b * 64 + cout) * HW + p] = acc[m][r];
        }
    }
}

// ---------------------------------------------------------------------------
extern "C" void kernel_launch(void* const* d_in, const int* in_sizes, int n_in,
                              void* d_out, int out_size, void* d_ws, size_t ws_size,
                              hipStream_t stream) {
    const float* x        = (const float*)d_in[0];
    const float* weight   = (const float*)d_in[1];
    const float* bias     = (const float*)d_in[2];
    const float* offset_w = (const float*)d_in[3];
    const float* offset_b = (const float*)d_in[4];
    float* out = (float*)d_out;

    unsigned int* xT = (unsigned int*)d_ws;                                // B*HW*32 u32 = 16MB
    unsigned short* wA  = (unsigned short*)(xT + (size_t)BATCH * HW * 32); // 4608*8
    unsigned short* owA = wA + 4608 * 8;                                   // 2304*8

    prep_kernel<<<27, 256, 0, stream>>>(weight, offset_w, wA, owA);

    int n_tiles = BATCH * HW / 64;   // 2048
    transform_kernel<<<n_tiles, 256, 0, stream>>>(x, xT);

    int n_blocks = BATCH * HW / 128; // 1024 blocks = 8 images x 128 tiles (8x16 px)
    fused_kernel<<<n_blocks, 256, 0, stream>>>(xT, wA, owA, bias, offset_b, out);
}

// Round 12
// 58.995 us; speedup vs baseline: 1.0805x; 1.0805x over previous
//
#include <hip/hip_runtime.h>
#include <hip/hip_bf16.h>
#include <math.h>

#define HH 128
#define WW 128
#define HW 16384
#define BATCH 8

// 2D tile geometry (fused kernel)
#define TR 8            // tile rows per block
#define TC 16           // tile cols per block
#define HALO 2
#define PR 12           // TR + 2*HALO
#define PC 20           // TC + 2*HALO
#define NPX (PR * PC)   // 240 patch pixels, 128B each (32 dwords, no pad)

typedef __attribute__((ext_vector_type(8))) short short8;
typedef __attribute__((ext_vector_type(16))) float f32x16;
typedef __attribute__((ext_vector_type(4))) unsigned int u32x4;
typedef __attribute__((ext_vector_type(2))) float f32x2;

union FragU { short8 v; unsigned int u[4]; u32x4 q; };

static __device__ __forceinline__ unsigned short f2bf(float f) {
    __hip_bfloat16 h = __float2bfloat16(f);
    return *(unsigned short*)&h;
}
static __device__ __forceinline__ float bf2f(unsigned short u) {
    return __uint_as_float(((unsigned int)u) << 16);
}
// unpack a bf16 channel-pair into {even, odd} as f32x2
static __device__ __forceinline__ f32x2 upk2(unsigned int r) {
    f32x2 v;
    v.x = __uint_as_float(r << 16);
    v.y = __uint_as_float(r & 0xffff0000u);
    return v;
}
// packed-f32 bilerp: v_pk_fma_f32 path (r11-proven, spill was unrelated)
static __device__ __forceinline__ short8 bilerp_frag(
    u32x4 r00, u32x4 r01, u32x4 r10, u32x4 r11,
    float w0, float w1, float w2, float w3)
{
    FragU bf;
    f32x2 W0 = {w0, w0}, W1 = {w1, w1}, W2 = {w2, w2}, W3 = {w3, w3};
#pragma unroll
    for (int d = 0; d < 4; ++d) {
        f32x2 s = upk2(r00[d]) * W0;
        s = __builtin_elementwise_fma(upk2(r01[d]), W1, s);
        s = __builtin_elementwise_fma(upk2(r10[d]), W2, s);
        s = __builtin_elementwise_fma(upk2(r11[d]), W3, s);
        float2 f2; f2.x = s.x; f2.y = s.y;
        __hip_bfloat162 h2 = __float22bfloat162_rn(f2);
        bf.u[d] = *(unsigned int*)&h2;
    }
    return bf.v;
}

// XOR-swizzled patch addressing (T2, both sides): pixel-major, 32 dwords/px;
// chunk c (4 dwords) lives at slot (c ^ (px&7)). Reads at fixed c spread 8
// consecutive px across all 8 bank-groups -> 2 lanes/group = conflict-free.
#define PADDR(PX, C) (((PX) << 5) + ((((C) ^ ((PX) & 7))) << 2))

// ---------------------------------------------------------------------------
// Prep: pack weights for 32x32x16 MFMA A-operand, bf16 (verified r8).
// A lane l: row = l&31, k-elems j=0..7 -> channel c = s*16 + 8*(l>>5) + j
//   wA : (m=2, kk=9, s=4, lane=64, j=8) bf16   <- weight (64,64,3,3)
//   owA: (kk=9, s=4, lane=64, j=8)      bf16   <- offset_w (27,64,3,3)
// ---------------------------------------------------------------------------
__global__ __launch_bounds__(256) void prep_kernel(
    const float* __restrict__ weight,
    const float* __restrict__ offset_w,
    unsigned short* __restrict__ wA,
    unsigned short* __restrict__ owA)
{
    int id = blockIdx.x * 256 + threadIdx.x;
    if (id < 4608) {                        // 2*9*4*64
        int m = id / 2304;
        int rem = id % 2304;
        int kk = rem >> 8;
        int s = (rem >> 6) & 3;
        int l = id & 63;
        int cout = m * 32 + (l & 31);
        int cbase = s * 16 + 8 * (l >> 5);
#pragma unroll
        for (int j = 0; j < 8; ++j) {
            wA[id * 8 + j] = f2bf(weight[(cout * 64 + cbase + j) * 9 + kk]);
        }
        return;
    }
    int id2 = id - 4608;
    if (id2 < 2304) {                       // 9*4*64
        int kk = id2 >> 8;
        int s = (id2 >> 6) & 3;
        int l = id2 & 63;
        int cout = l & 31;
        int cbase = s * 16 + 8 * (l >> 5);
#pragma unroll
        for (int j = 0; j < 8; ++j) {
            float v = (cout < 27) ? offset_w[(cout * 64 + cbase + j) * 9 + kk] : 0.0f;
            owA[id2 * 8 + j] = f2bf(v);
        }
    }
}

// ---------------------------------------------------------------------------
// Transform: x NCHW fp32 -> xT NHWC bf16 (u32 channel-pairs), LDS-tiled.
// ---------------------------------------------------------------------------
__global__ __launch_bounds__(256) void transform_kernel(
    const float* __restrict__ x,
    unsigned int* __restrict__ xT)
{
    __shared__ unsigned int lds[64][33];
    int bid = blockIdx.x;
    int b = bid & 7;                        // image -> XCD
    int pix0 = (bid >> 3) << 6;
    int t = threadIdx.x;
    int px = t & 63;
    int cp0 = (t >> 6) * 8;

    const float* xb = x + (size_t)b * 64 * HW + pix0 + px;
#pragma unroll
    for (int it = 0; it < 8; ++it) {
        int cpair = cp0 + it;
        float2 f2;
        f2.x = xb[(size_t)(2 * cpair) * HW];
        f2.y = xb[(size_t)(2 * cpair + 1) * HW];
        __hip_bfloat162 h2 = __float22bfloat162_rn(f2);
        lds[px][cpair] = *(unsigned int*)&h2;
    }
    __syncthreads();

    int wpx = t >> 2, qq = t & 3;
    unsigned int* dst = xT + ((size_t)b * HW + pix0 + wpx) * 32 + qq * 8;
    u32x4 a, c;
#pragma unroll
    for (int j = 0; j < 4; ++j) a[j] = lds[wpx][qq * 8 + j];
#pragma unroll
    for (int j = 0; j < 4; ++j) c[j] = lds[wpx][qq * 8 + 4 + j];
    *(u32x4*)dst = a;
    *(u32x4*)(dst + 4) = c;
}

// ---------------------------------------------------------------------------
// Fused kernel, LDS-patch v4.
//   vs r10 (45us, proven no-spill structure):
//   (a) patch: XOR-swizzled chunk placement (PADDR) -> ds_read_b128 bank
//       conflicts ~0; 30.72KB (no pad).
//   (b) red: bf16 (offsets sigma~0.24, rel err 2^-9 -> ~5e-3 output) -> 6.9KB.
//   LDS total 37.6KB -> 4 blocks/CU (grid = exactly 4/CU, no tail), 16 waves.
//   (c) pk_fma bilerp kept from r11.
//   acc1 still dies into red before phase 2 (r11's spill avoided).
// ---------------------------------------------------------------------------
__global__ __launch_bounds__(256, 4) void fused_kernel(
    const unsigned int* __restrict__ xT,    // NHWC bf16
    const unsigned short* __restrict__ wA,  // (2,9,4,64,8) bf16
    const unsigned short* __restrict__ owA, // (9,4,64,8) bf16
    const float* __restrict__ bias,         // (64,)
    const float* __restrict__ offset_b,     // (27,)
    float* __restrict__ out)                // (B,64,HW) f32
{
    __shared__ unsigned int patch[NPX * 32];        // 30.72 KB, swizzled
    __shared__ unsigned short red[4][27][32];       // 6.91 KB per-wave off/mask

    int t = threadIdx.x;
    int lane = t & 63;
    int wid = t >> 6;
    int bid = blockIdx.x;
    int b = bid & 7;                        // image -> XCD
    int tile = bid >> 3;                    // 0..127
    int ho0 = (tile >> 3) * TR;
    int wo0 = (tile & 7) * TC;
    int py0 = ho0 - HALO;
    int px0 = wo0 - HALO;

    int q = lane & 31;                      // pixel within wave
    int hi = lane >> 5;                     // channel-half
    int ho = ho0 + 2 * wid + (q >> 4);
    int wo = wo0 + (q & 15);
    int p = ho * WW + wo;

    const unsigned int* xb = xT + (size_t)b * HW * 32;
    const short8* wAv = (const short8*)wA;
    const short8* owAv = (const short8*)owA;

    // ---------------- stage patch (coalesced global, swizzled LDS) --------
#pragma unroll
    for (int it = 0; it < 8; ++it) {
        int id = it * 256 + t;
        if (id < NPX * 8) {                 // 1920 16B-chunks
            int px = id >> 3;               // pixel-major: 8 lanes = 1 pixel
            int c = id & 7;
            int row = px / PC;
            int col = px - row * PC;
            int yc = min(max(py0 + row, 0), HH - 1);
            int xc = min(max(px0 + col, 0), WW - 1);
            u32x4 v = *(const u32x4*)(xb + (size_t)(yc * WW + xc) * 32 + c * 4);
            *(u32x4*)&patch[PADDR(px, c)] = v;
        }
    }
    __syncthreads();                        // the ONLY barrier

    // ---------------- phase 1: offset conv ----------------
    {
        f32x16 acc1 = {};
#pragma unroll
        for (int kk = 0; kk < 9; ++kk) {
            int iy = ho + kk / 3 - 1;
            int ix = wo + kk % 3 - 1;
            bool ok = ((unsigned)iy < 128u) && ((unsigned)ix < 128u);
            int jy = min(max(iy, 0), 127) - py0;
            int jx = min(max(ix, 0), 127) - px0;
            int ptap = jy * PC + jx;
#pragma unroll
            for (int s = 0; s < 4; ++s) {
                u32x4 raw = *(const u32x4*)&patch[PADDR(ptap, 2 * s + hi)];
                FragU bf;
#pragma unroll
                for (int j = 0; j < 4; ++j) bf.u[j] = ok ? raw[j] : 0u;
                acc1 = __builtin_amdgcn_mfma_f32_32x32x16_bf16(
                    owAv[(kk * 4 + s) * 64 + lane], bf.v, acc1, 0, 0, 0);
            }
        }
        // bias + sigmoid -> per-wave bf16 LDS slice; acc1 dies here.
#pragma unroll
        for (int r = 0; r < 16; ++r) {
            int cout = (r & 3) + 8 * (r >> 2) + 4 * hi;
            if (cout < 27) {
                float a = acc1[r] + offset_b[cout];
                if (cout >= 18) a = 1.0f / (1.0f + __expf(-a));
                red[wid][cout][q] = f2bf(a);
            }
        }
    }

    // ---------------- phase 2: deformable conv ----------------
    f32x16 acc[2];
#pragma unroll
    for (int m = 0; m < 2; ++m) {
#pragma unroll
        for (int r = 0; r < 16; ++r) {
            acc[m][r] = bias[m * 32 + (r & 3) + 8 * (r >> 2) + 4 * hi];
        }
    }

    for (int kk = 0; kk < 9; ++kk) {
        float dy = bf2f(red[wid][2 * kk][q]);
        float dx = bf2f(red[wid][2 * kk + 1][q]);
        float mm = bf2f(red[wid][18 + kk][q]);

        float py = dy + (float)(kk / 3 + ho - 1);
        float px = dx + (float)(kk % 3 + wo - 1);
        float y0f = floorf(py), x0f = floorf(px);
        float wy = py - y0f, wx = px - x0f;
        int y0 = (int)y0f, x0 = (int)x0f;
        int y1 = y0 + 1, x1 = x0 + 1;
        bool y0ok = (unsigned)y0 < 128u, y1ok = (unsigned)y1 < 128u;
        bool x0ok = (unsigned)x0 < 128u, x1ok = (unsigned)x1 < 128u;
        float w0 = (y0ok && x0ok) ? (1.0f - wy) * (1.0f - wx) * mm : 0.0f;
        float w1 = (y0ok && x1ok) ? (1.0f - wy) * wx * mm : 0.0f;
        float w2 = (y1ok && x0ok) ? wy * (1.0f - wx) * mm : 0.0f;
        float w3 = (y1ok && x1ok) ? wy * wx * mm : 0.0f;
        int y0c = min(max(y0, 0), 127), y1c = min(max(y1, 0), 127);
        int x0c = min(max(x0, 0), 127), x1c = min(max(x1, 0), 127);

        int jy0 = y0c - py0, jy1 = y1c - py0;
        int jx0 = x0c - px0, jx1 = x1c - px0;
        bool inp = ((unsigned)jy0 < (unsigned)PR) && ((unsigned)jy1 < (unsigned)PR) &&
                   ((unsigned)jx0 < (unsigned)PC) && ((unsigned)jx1 < (unsigned)PC);

        // A-frags loaded just-in-time inside each step: only 2 live at once.
#define P2_STEP(S, R00, R01, R10, R11) {                                    \
            short8 A0 = wAv[(kk * 4 + (S)) * 64 + lane];                    \
            short8 A1 = wAv[(36 + kk * 4 + (S)) * 64 + lane];               \
            short8 bf = bilerp_frag(R00, R01, R10, R11, w0, w1, w2, w3);    \
            acc[0] = __builtin_amdgcn_mfma_f32_32x32x16_bf16(A0, bf, acc[0], 0, 0, 0); \
            acc[1] = __builtin_amdgcn_mfma_f32_32x32x16_bf16(A1, bf, acc[1], 0, 0, 0); \
        }

        if (__all(inp)) {
            int p00 = jy0 * PC + jx0;
            int p01 = jy0 * PC + jx1;
            int p10 = jy1 * PC + jx0;
            int p11 = jy1 * PC + jx1;
#define LRD(PX, S) (*(const u32x4*)&patch[PADDR(PX, 2 * (S) + hi)])
            P2_STEP(0, LRD(p00,0), LRD(p01,0), LRD(p10,0), LRD(p11,0));
            P2_STEP(1, LRD(p00,1), LRD(p01,1), LRD(p10,1), LRD(p11,1));
            P2_STEP(2, LRD(p00,2), LRD(p01,2), LRD(p10,2), LRD(p11,2));
            P2_STEP(3, LRD(p00,3), LRD(p01,3), LRD(p10,3), LRD(p11,3));
#undef LRD
        } else {
            int o00 = (y0c * WW + x0c) * 32 + (hi << 2);
            int o01 = (y0c * WW + x1c) * 32 + (hi << 2);
            int o10 = (y1c * WW + x0c) * 32 + (hi << 2);
            int o11 = (y1c * WW + x1c) * 32 + (hi << 2);
#define GRD(O, S) (*(const u32x4*)(xb + (O) + (S) * 8))
            P2_STEP(0, GRD(o00,0), GRD(o01,0), GRD(o10,0), GRD(o11,0));
            P2_STEP(1, GRD(o00,1), GRD(o01,1), GRD(o10,1), GRD(o11,1));
            P2_STEP(2, GRD(o00,2), GRD(o01,2), GRD(o10,2), GRD(o11,2));
            P2_STEP(3, GRD(o00,3), GRD(o01,3), GRD(o10,3), GRD(o11,3));
#undef GRD
        }
#undef P2_STEP
    }

    // D: row(cout) = m*32 + (r&3)+8*(r>>2)+4*hi, col(pixel) = q
#pragma unroll
    for (int m = 0; m < 2; ++m) {
#pragma unroll
        for (int r = 0; r < 16; ++r) {
            int cout = m * 32 + (r & 3) + 8 * (r >> 2) + 4 * hi;
            out[((size_t)b * 64 + cout) * HW + p] = acc[m][r];
        }
    }
}

// ---------------------------------------------------------------------------
extern "C" void kernel_launch(void* const* d_in, const int* in_sizes, int n_in,
                              void* d_out, int out_size, void* d_ws, size_t ws_size,
                              hipStream_t stream) {
    const float* x        = (const float*)d_in[0];
    const float* weight   = (const float*)d_in[1];
    const float* bias     = (const float*)d_in[2];
    const float* offset_w = (const float*)d_in[3];
    const float* offset_b = (const float*)d_in[4];
    float* out = (float*)d_out;

    unsigned int* xT = (unsigned int*)d_ws;                                // B*HW*32 u32 = 16MB
    unsigned short* wA  = (unsigned short*)(xT + (size_t)BATCH * HW * 32); // 4608*8
    unsigned short* owA = wA + 4608 * 8;                                   // 2304*8

    prep_kernel<<<27, 256, 0, stream>>>(weight, offset_w, wA, owA);

    int n_tiles = BATCH * HW / 64;   // 2048
    transform_kernel<<<n_tiles, 256, 0, stream>>>(x, xT);

    int n_blocks = BATCH * HW / 128; // 1024 blocks = 8 images x 128 tiles (8x16 px)
    fused_kernel<<<n_blocks, 256, 0, stream>>>(xT, wA, owA, bias, offset_b, out);
}

// Round 13
// 57.442 us; speedup vs baseline: 1.1097x; 1.0270x over previous
//
#include <hip/hip_runtime.h>
#include <hip/hip_bf16.h>
#include <math.h>

#define HH 128
#define WW 128
#define HW 16384
#define BATCH 8

// 2D tile geometry (fused kernel)
#define TR 8            // tile rows per block
#define TC 16           // tile cols per block
#define HALO 2
#define PR 12           // TR + 2*HALO
#define PC 20           // TC + 2*HALO
#define NPX (PR * PC)   // 240 patch pixels
#define PST 34          // dwords per patch pixel: 34 = 2 mod 32 -> pixel base
                        // bank advances by 2 per px -> any 16 consecutive px
                        // cover 32 banks exactly 2-way on ds_read_b128 (free)

typedef __attribute__((ext_vector_type(8))) short short8;
typedef __attribute__((ext_vector_type(16))) float f32x16;
typedef __attribute__((ext_vector_type(4))) unsigned int u32x4;
typedef __attribute__((ext_vector_type(2))) float f32x2;

union FragU { short8 v; unsigned int u[4]; u32x4 q; };

static __device__ __forceinline__ unsigned short f2bf(float f) {
    __hip_bfloat16 h = __float2bfloat16(f);
    return *(unsigned short*)&h;
}
static __device__ __forceinline__ float bf2f(unsigned short u) {
    return __uint_as_float(((unsigned int)u) << 16);
}
// unpack a bf16 channel-pair into {even, odd} as f32x2
static __device__ __forceinline__ f32x2 upk2(unsigned int r) {
    f32x2 v;
    v.x = __uint_as_float(r << 16);
    v.y = __uint_as_float(r & 0xffff0000u);
    return v;
}
// packed-f32 bilerp (v_pk_fma_f32)
static __device__ __forceinline__ short8 bilerp_frag(
    u32x4 r00, u32x4 r01, u32x4 r10, u32x4 r11,
    float w0, float w1, float w2, float w3)
{
    FragU bf;
    f32x2 W0 = {w0, w0}, W1 = {w1, w1}, W2 = {w2, w2}, W3 = {w3, w3};
#pragma unroll
    for (int d = 0; d < 4; ++d) {
        f32x2 s = upk2(r00[d]) * W0;
        s = __builtin_elementwise_fma(upk2(r01[d]), W1, s);
        s = __builtin_elementwise_fma(upk2(r10[d]), W2, s);
        s = __builtin_elementwise_fma(upk2(r11[d]), W3, s);
        float2 f2; f2.x = s.x; f2.y = s.y;
        __hip_bfloat162 h2 = __float22bfloat162_rn(f2);
        bf.u[d] = *(unsigned int*)&h2;
    }
    return bf.v;
}

// plain stride-34 patch addressing (no XOR; bank spread comes from stride)
#define PADDR(PX, C) ((PX) * PST + ((C) << 2))

// ---------------------------------------------------------------------------
// Prep: pack weights for 32x32x16 MFMA A-operand, bf16 (verified r8).
// A lane l: row = l&31, k-elems j=0..7 -> channel c = s*16 + 8*(l>>5) + j
//   wA : (m=2, kk=9, s=4, lane=64, j=8) bf16   <- weight (64,64,3,3)
//   owA: (kk=9, s=4, lane=64, j=8)      bf16   <- offset_w (27,64,3,3)
// ---------------------------------------------------------------------------
__global__ __launch_bounds__(256) void prep_kernel(
    const float* __restrict__ weight,
    const float* __restrict__ offset_w,
    unsigned short* __restrict__ wA,
    unsigned short* __restrict__ owA)
{
    int id = blockIdx.x * 256 + threadIdx.x;
    if (id < 4608) {                        // 2*9*4*64
        int m = id / 2304;
        int rem = id % 2304;
        int kk = rem >> 8;
        int s = (rem >> 6) & 3;
        int l = id & 63;
        int cout = m * 32 + (l & 31);
        int cbase = s * 16 + 8 * (l >> 5);
#pragma unroll
        for (int j = 0; j < 8; ++j) {
            wA[id * 8 + j] = f2bf(weight[(cout * 64 + cbase + j) * 9 + kk]);
        }
        return;
    }
    int id2 = id - 4608;
    if (id2 < 2304) {                       // 9*4*64
        int kk = id2 >> 8;
        int s = (id2 >> 6) & 3;
        int l = id2 & 63;
        int cout = l & 31;
        int cbase = s * 16 + 8 * (l >> 5);
#pragma unroll
        for (int j = 0; j < 8; ++j) {
            float v = (cout < 27) ? offset_w[(cout * 64 + cbase + j) * 9 + kk] : 0.0f;
            owA[id2 * 8 + j] = f2bf(v);
        }
    }
}

// ---------------------------------------------------------------------------
// Transform: x NCHW fp32 -> xT NHWC bf16 (u32 channel-pairs), LDS-tiled.
// ---------------------------------------------------------------------------
__global__ __launch_bounds__(256) void transform_kernel(
    const float* __restrict__ x,
    unsigned int* __restrict__ xT)
{
    __shared__ unsigned int lds[64][33];
    int bid = blockIdx.x;
    int b = bid & 7;                        // image -> XCD
    int pix0 = (bid >> 3) << 6;
    int t = threadIdx.x;
    int px = t & 63;
    int cp0 = (t >> 6) * 8;

    const float* xb = x + (size_t)b * 64 * HW + pix0 + px;
#pragma unroll
    for (int it = 0; it < 8; ++it) {
        int cpair = cp0 + it;
        float2 f2;
        f2.x = xb[(size_t)(2 * cpair) * HW];
        f2.y = xb[(size_t)(2 * cpair + 1) * HW];
        __hip_bfloat162 h2 = __float22bfloat162_rn(f2);
        lds[px][cpair] = *(unsigned int*)&h2;
    }
    __syncthreads();

    int wpx = t >> 2, qq = t & 3;
    unsigned int* dst = xT + ((size_t)b * HW + pix0 + wpx) * 32 + qq * 8;
    u32x4 a, c;
#pragma unroll
    for (int j = 0; j < 4; ++j) a[j] = lds[wpx][qq * 8 + j];
#pragma unroll
    for (int j = 0; j < 4; ++j) c[j] = lds[wpx][qq * 8 + 4 + j];
    *(u32x4*)dst = a;
    *(u32x4*)(dst + 4) = c;
}

// ---------------------------------------------------------------------------
// Fused kernel, LDS-patch v5.
//   vs r12: patch stride 34 dwords (2 mod 32), no XOR swizzle. The 32-dword
//   (and 36-dword) strides both collapsed pixel bases onto 8 bank-groups ->
//   structural 4-way conflicts on ds_read_b128 (measured 4.2M/6.0M cycles).
//   Stride 34 gives 16 distinct even base-banks per 16-lane phase -> 2-way
//   everywhere (free, m136). Everything else identical to r12 (no-spill).
// ---------------------------------------------------------------------------
__global__ __launch_bounds__(256, 4) void fused_kernel(
    const unsigned int* __restrict__ xT,    // NHWC bf16
    const unsigned short* __restrict__ wA,  // (2,9,4,64,8) bf16
    const unsigned short* __restrict__ owA, // (9,4,64,8) bf16
    const float* __restrict__ bias,         // (64,)
    const float* __restrict__ offset_b,     // (27,)
    float* __restrict__ out)                // (B,64,HW) f32
{
    __shared__ unsigned int patch[NPX * PST];       // 32.64 KB
    __shared__ unsigned short red[4][27][32];       // 6.91 KB per-wave off/mask

    int t = threadIdx.x;
    int lane = t & 63;
    int wid = t >> 6;
    int bid = blockIdx.x;
    int b = bid & 7;                        // image -> XCD
    int tile = bid >> 3;                    // 0..127
    int ho0 = (tile >> 3) * TR;
    int wo0 = (tile & 7) * TC;
    int py0 = ho0 - HALO;
    int px0 = wo0 - HALO;

    int q = lane & 31;                      // pixel within wave
    int hi = lane >> 5;                     // channel-half
    int ho = ho0 + 2 * wid + (q >> 4);
    int wo = wo0 + (q & 15);
    int p = ho * WW + wo;

    const unsigned int* xb = xT + (size_t)b * HW * 32;
    const short8* wAv = (const short8*)wA;
    const short8* owAv = (const short8*)owA;

    // ---------------- stage patch (coalesced global -> stride-34 LDS) -----
#pragma unroll
    for (int it = 0; it < 8; ++it) {
        int id = it * 256 + t;
        if (id < NPX * 8) {                 // 1920 16B-chunks
            int px = id >> 3;               // 8 lanes = 1 pixel
            int c = id & 7;
            int row = px / PC;
            int col = px - row * PC;
            int yc = min(max(py0 + row, 0), HH - 1);
            int xc = min(max(px0 + col, 0), WW - 1);
            u32x4 v = *(const u32x4*)(xb + (size_t)(yc * WW + xc) * 32 + c * 4);
            *(u32x4*)&patch[PADDR(px, c)] = v;
        }
    }
    __syncthreads();                        // the ONLY barrier

    // ---------------- phase 1: offset conv ----------------
    {
        f32x16 acc1 = {};
#pragma unroll
        for (int kk = 0; kk < 9; ++kk) {
            int iy = ho + kk / 3 - 1;
            int ix = wo + kk % 3 - 1;
            bool ok = ((unsigned)iy < 128u) && ((unsigned)ix < 128u);
            int jy = min(max(iy, 0), 127) - py0;
            int jx = min(max(ix, 0), 127) - px0;
            int ptap = jy * PC + jx;
#pragma unroll
            for (int s = 0; s < 4; ++s) {
                u32x4 raw = *(const u32x4*)&patch[PADDR(ptap, 2 * s + hi)];
                FragU bf;
#pragma unroll
                for (int j = 0; j < 4; ++j) bf.u[j] = ok ? raw[j] : 0u;
                acc1 = __builtin_amdgcn_mfma_f32_32x32x16_bf16(
                    owAv[(kk * 4 + s) * 64 + lane], bf.v, acc1, 0, 0, 0);
            }
        }
        // bias + sigmoid -> per-wave bf16 LDS slice; acc1 dies here.
#pragma unroll
        for (int r = 0; r < 16; ++r) {
            int cout = (r & 3) + 8 * (r >> 2) + 4 * hi;
            if (cout < 27) {
                float a = acc1[r] + offset_b[cout];
                if (cout >= 18) a = 1.0f / (1.0f + __expf(-a));
                red[wid][cout][q] = f2bf(a);
            }
        }
    }

    // ---------------- phase 2: deformable conv ----------------
    f32x16 acc[2];
#pragma unroll
    for (int m = 0; m < 2; ++m) {
#pragma unroll
        for (int r = 0; r < 16; ++r) {
            acc[m][r] = bias[m * 32 + (r & 3) + 8 * (r >> 2) + 4 * hi];
        }
    }

    for (int kk = 0; kk < 9; ++kk) {
        float dy = bf2f(red[wid][2 * kk][q]);
        float dx = bf2f(red[wid][2 * kk + 1][q]);
        float mm = bf2f(red[wid][18 + kk][q]);

        float py = dy + (float)(kk / 3 + ho - 1);
        float px = dx + (float)(kk % 3 + wo - 1);
        float y0f = floorf(py), x0f = floorf(px);
        float wy = py - y0f, wx = px - x0f;
        int y0 = (int)y0f, x0 = (int)x0f;
        int y1 = y0 + 1, x1 = x0 + 1;
        bool y0ok = (unsigned)y0 < 128u, y1ok = (unsigned)y1 < 128u;
        bool x0ok = (unsigned)x0 < 128u, x1ok = (unsigned)x1 < 128u;
        float w0 = (y0ok && x0ok) ? (1.0f - wy) * (1.0f - wx) * mm : 0.0f;
        float w1 = (y0ok && x1ok) ? (1.0f - wy) * wx * mm : 0.0f;
        float w2 = (y1ok && x0ok) ? wy * (1.0f - wx) * mm : 0.0f;
        float w3 = (y1ok && x1ok) ? wy * wx * mm : 0.0f;
        int y0c = min(max(y0, 0), 127), y1c = min(max(y1, 0), 127);
        int x0c = min(max(x0, 0), 127), x1c = min(max(x1, 0), 127);

        int jy0 = y0c - py0, jy1 = y1c - py0;
        int jx0 = x0c - px0, jx1 = x1c - px0;
        bool inp = ((unsigned)jy0 < (unsigned)PR) && ((unsigned)jy1 < (unsigned)PR) &&
                   ((unsigned)jx0 < (unsigned)PC) && ((unsigned)jx1 < (unsigned)PC);

        // A-frags loaded just-in-time inside each step: only 2 live at once.
#define P2_STEP(S, R00, R01, R10, R11) {                                    \
            short8 A0 = wAv[(kk * 4 + (S)) * 64 + lane];                    \
            short8 A1 = wAv[(36 + kk * 4 + (S)) * 64 + lane];               \
            short8 bf = bilerp_frag(R00, R01, R10, R11, w0, w1, w2, w3);    \
            acc[0] = __builtin_amdgcn_mfma_f32_32x32x16_bf16(A0, bf, acc[0], 0, 0, 0); \
            acc[1] = __builtin_amdgcn_mfma_f32_32x32x16_bf16(A1, bf, acc[1], 0, 0, 0); \
        }

        if (__all(inp)) {
            int p00 = jy0 * PC + jx0;
            int p01 = jy0 * PC + jx1;
            int p10 = jy1 * PC + jx0;
            int p11 = jy1 * PC + jx1;
#define LRD(PX, S) (*(const u32x4*)&patch[PADDR(PX, 2 * (S) + hi)])
            P2_STEP(0, LRD(p00,0), LRD(p01,0), LRD(p10,0), LRD(p11,0));
            P2_STEP(1, LRD(p00,1), LRD(p01,1), LRD(p10,1), LRD(p11,1));
            P2_STEP(2, LRD(p00,2), LRD(p01,2), LRD(p10,2), LRD(p11,2));
            P2_STEP(3, LRD(p00,3), LRD(p01,3), LRD(p10,3), LRD(p11,3));
#undef LRD
        } else {
            int o00 = (y0c * WW + x0c) * 32 + (hi << 2);
            int o01 = (y0c * WW + x1c) * 32 + (hi << 2);
            int o10 = (y1c * WW + x0c) * 32 + (hi << 2);
            int o11 = (y1c * WW + x1c) * 32 + (hi << 2);
#define GRD(O, S) (*(const u32x4*)(xb + (O) + (S) * 8))
            P2_STEP(0, GRD(o00,0), GRD(o01,0), GRD(o10,0), GRD(o11,0));
            P2_STEP(1, GRD(o00,1), GRD(o01,1), GRD(o10,1), GRD(o11,1));
            P2_STEP(2, GRD(o00,2), GRD(o01,2), GRD(o10,2), GRD(o11,2));
            P2_STEP(3, GRD(o00,3), GRD(o01,3), GRD(o10,3), GRD(o11,3));
#undef GRD
        }
#undef P2_STEP
    }

    // D: row(cout) = m*32 + (r&3)+8*(r>>2)+4*hi, col(pixel) = q
#pragma unroll
    for (int m = 0; m < 2; ++m) {
#pragma unroll
        for (int r = 0; r < 16; ++r) {
            int cout = m * 32 + (r & 3) + 8 * (r >> 2) + 4 * hi;
            out[((size_t)b * 64 + cout) * HW + p] = acc[m][r];
        }
    }
}

// ---------------------------------------------------------------------------
extern "C" void kernel_launch(void* const* d_in, const int* in_sizes, int n_in,
                              void* d_out, int out_size, void* d_ws, size_t ws_size,
                              hipStream_t stream) {
    const float* x        = (const float*)d_in[0];
    const float* weight   = (const float*)d_in[1];
    const float* bias     = (const float*)d_in[2];
    const float* offset_w = (const float*)d_in[3];
    const float* offset_b = (const float*)d_in[4];
    float* out = (float*)d_out;

    unsigned int* xT = (unsigned int*)d_ws;                                // B*HW*32 u32 = 16MB
    unsigned short* wA  = (unsigned short*)(xT + (size_t)BATCH * HW * 32); // 4608*8
    unsigned short* owA = wA + 4608 * 8;                                   // 2304*8

    prep_kernel<<<27, 256, 0, stream>>>(weight, offset_w, wA, owA);

    int n_tiles = BATCH * HW / 64;   // 2048
    transform_kernel<<<n_tiles, 256, 0, stream>>>(x, xT);

    int n_blocks = BATCH * HW / 128; // 1024 blocks = 8 images x 128 tiles (8x16 px)
    fused_kernel<<<n_blocks, 256, 0, stream>>>(xT, wA, owA, bias, offset_b, out);
}

// Round 14
// 52.646 us; speedup vs baseline: 1.2108x; 1.0911x over previous
//
#include <hip/hip_runtime.h>
#include <hip/hip_bf16.h>
#include <math.h>

#define HH 128
#define WW 128
#define HW 16384
#define BATCH 8

// 2D tile geometry (fused kernel)
#define TR 8            // tile rows per block
#define TC 16           // tile cols per block
#define HALO 2
#define PR 12           // TR + 2*HALO
#define PC 20           // TC + 2*HALO
#define NPX (PR * PC)   // 240 patch pixels
#define PST 34          // dwords/px: 2 mod 32 -> 2-way banks on b128 (free)

typedef __attribute__((ext_vector_type(8))) _Float16 f16x8;
typedef __attribute__((ext_vector_type(2))) _Float16 f16x2;
typedef __attribute__((ext_vector_type(16))) float f32x16;
typedef __attribute__((ext_vector_type(4))) unsigned int u32x4;

union FragU { f16x8 v; unsigned int u[4]; u32x4 q; f16x2 h[4]; };

static __device__ __forceinline__ unsigned short f2h(float f) {
    _Float16 h = (_Float16)f;
    return *(unsigned short*)&h;
}
static __device__ __forceinline__ float h2f(unsigned short u) {
    _Float16 h = *(_Float16*)&u;
    return (float)h;
}

// f16 packed bilerp: 4 v_pk_fma_f16 per channel-pair, ZERO unpack/convert.
// Output is directly the MFMA B-fragment.
static __device__ __forceinline__ f16x8 bilerp_frag(
    u32x4 r00, u32x4 r01, u32x4 r10, u32x4 r11,
    f16x2 W0, f16x2 W1, f16x2 W2, f16x2 W3)
{
    FragU a, b, c, d, bf;
    a.q = r00; b.q = r01; c.q = r10; d.q = r11;
#pragma unroll
    for (int i = 0; i < 4; ++i) {
        f16x2 s = a.h[i] * W0;
        s = __builtin_elementwise_fma(b.h[i], W1, s);
        s = __builtin_elementwise_fma(c.h[i], W2, s);
        s = __builtin_elementwise_fma(d.h[i], W3, s);
        bf.h[i] = s;
    }
    return bf.v;
}

// plain stride-34 patch addressing
#define PADDR(PX, C) ((PX) * PST + ((C) << 2))

// ---------------------------------------------------------------------------
// Prep: pack weights for 32x32x16 MFMA A-operand, f16.
// A lane l: row = l&31, k-elems j=0..7 -> channel c = s*16 + 8*(l>>5) + j
//   wA : (m=2, kk=9, s=4, lane=64, j=8) f16   <- weight (64,64,3,3)
//   owA: (kk=9, s=4, lane=64, j=8)      f16   <- offset_w (27,64,3,3)
// ---------------------------------------------------------------------------
__global__ __launch_bounds__(256) void prep_kernel(
    const float* __restrict__ weight,
    const float* __restrict__ offset_w,
    unsigned short* __restrict__ wA,
    unsigned short* __restrict__ owA)
{
    int id = blockIdx.x * 256 + threadIdx.x;
    if (id < 4608) {                        // 2*9*4*64
        int m = id / 2304;
        int rem = id % 2304;
        int kk = rem >> 8;
        int s = (rem >> 6) & 3;
        int l = id & 63;
        int cout = m * 32 + (l & 31);
        int cbase = s * 16 + 8 * (l >> 5);
#pragma unroll
        for (int j = 0; j < 8; ++j) {
            wA[id * 8 + j] = f2h(weight[(cout * 64 + cbase + j) * 9 + kk]);
        }
        return;
    }
    int id2 = id - 4608;
    if (id2 < 2304) {                       // 9*4*64
        int kk = id2 >> 8;
        int s = (id2 >> 6) & 3;
        int l = id2 & 63;
        int cout = l & 31;
        int cbase = s * 16 + 8 * (l >> 5);
#pragma unroll
        for (int j = 0; j < 8; ++j) {
            float v = (cout < 27) ? offset_w[(cout * 64 + cbase + j) * 9 + kk] : 0.0f;
            owA[id2 * 8 + j] = f2h(v);
        }
    }
}

// ---------------------------------------------------------------------------
// Transform: x NCHW fp32 -> xT NHWC f16 (u32 channel-pairs), LDS-tiled.
// ---------------------------------------------------------------------------
__global__ __launch_bounds__(256) void transform_kernel(
    const float* __restrict__ x,
    unsigned int* __restrict__ xT)
{
    __shared__ unsigned int lds[64][33];
    int bid = blockIdx.x;
    int b = bid & 7;                        // image -> XCD
    int pix0 = (bid >> 3) << 6;
    int t = threadIdx.x;
    int px = t & 63;
    int cp0 = (t >> 6) * 8;

    const float* xb = x + (size_t)b * 64 * HW + pix0 + px;
#pragma unroll
    for (int it = 0; it < 8; ++it) {
        int cpair = cp0 + it;
        float lo = xb[(size_t)(2 * cpair) * HW];
        float hi = xb[(size_t)(2 * cpair + 1) * HW];
        lds[px][cpair] = ((unsigned int)f2h(hi) << 16) | f2h(lo);
    }
    __syncthreads();

    int wpx = t >> 2, qq = t & 3;
    unsigned int* dst = xT + ((size_t)b * HW + pix0 + wpx) * 32 + qq * 8;
    u32x4 a, c;
#pragma unroll
    for (int j = 0; j < 4; ++j) a[j] = lds[wpx][qq * 8 + j];
#pragma unroll
    for (int j = 0; j < 4; ++j) c[j] = lds[wpx][qq * 8 + 4 + j];
    *(u32x4*)dst = a;
    *(u32x4*)(dst + 4) = c;
}

// ---------------------------------------------------------------------------
// Fused kernel, LDS-patch v6 (f16 datapath).
//   vs r13: (a) patch/weights/MFMA all f16 -> bilerp is pure v_pk_fma_f16
//   (4 ops per channel-pair, no unpack, no repack; output IS the B-frag).
//   (b) OOB patch pixels staged as ZERO -> phase 1 needs no ok/clamp/cndmask
//   (conv zero-padding falls out of the patch; phase-2 invalid corners have
//   w=0 so zeroed pixels are never consumed with nonzero weight).
//   Structure (stride-34 patch, per-wave f16 red, JIT A-frags, one barrier)
//   identical to r13's no-spill layout.
// ---------------------------------------------------------------------------
__global__ __launch_bounds__(256, 4) void fused_kernel(
    const unsigned int* __restrict__ xT,    // NHWC f16
    const unsigned short* __restrict__ wA,  // (2,9,4,64,8) f16
    const unsigned short* __restrict__ owA, // (9,4,64,8) f16
    const float* __restrict__ bias,         // (64,)
    const float* __restrict__ offset_b,     // (27,)
    float* __restrict__ out)                // (B,64,HW) f32
{
    __shared__ unsigned int patch[NPX * PST];       // 32.64 KB
    __shared__ unsigned short red[4][27][32];       // 6.91 KB per-wave off/mask

    int t = threadIdx.x;
    int lane = t & 63;
    int wid = t >> 6;
    int bid = blockIdx.x;
    int b = bid & 7;                        // image -> XCD
    int tile = bid >> 3;                    // 0..127
    int ho0 = (tile >> 3) * TR;
    int wo0 = (tile & 7) * TC;
    int py0 = ho0 - HALO;
    int px0 = wo0 - HALO;

    int q = lane & 31;                      // pixel within wave
    int hi = lane >> 5;                     // channel-half
    int ho = ho0 + 2 * wid + (q >> 4);
    int wo = wo0 + (q & 15);
    int p = ho * WW + wo;

    const unsigned int* xb = xT + (size_t)b * HW * 32;
    const f16x8* wAv = (const f16x8*)wA;
    const f16x8* owAv = (const f16x8*)owA;

    // ---------------- stage patch (coalesced; OOB pixels -> zero) ---------
#pragma unroll
    for (int it = 0; it < 8; ++it) {
        int id = it * 256 + t;
        if (id < NPX * 8) {                 // 1920 16B-chunks
            int px = id >> 3;               // 8 lanes = 1 pixel
            int c = id & 7;
            int row = px / PC;
            int col = px - row * PC;
            int iy = py0 + row;
            int ix = px0 + col;
            bool okpx = ((unsigned)iy < 128u) && ((unsigned)ix < 128u);
            int yc = min(max(iy, 0), HH - 1);
            int xc = min(max(ix, 0), WW - 1);
            u32x4 v = *(const u32x4*)(xb + (size_t)(yc * WW + xc) * 32 + c * 4);
#pragma unroll
            for (int j = 0; j < 4; ++j) v[j] = okpx ? v[j] : 0u;
            *(u32x4*)&patch[PADDR(px, c)] = v;
        }
    }
    __syncthreads();                        // the ONLY barrier

    // ---------------- phase 1: offset conv (no boundary code at all) ------
    {
        f32x16 acc1 = {};
#pragma unroll
        for (int kk = 0; kk < 9; ++kk) {
            int jy = ho + kk / 3 - 1 - py0;     // always within patch
            int jx = wo + kk % 3 - 1 - px0;
            int ptap = jy * PC + jx;
#pragma unroll
            for (int s = 0; s < 4; ++s) {
                FragU bf;
                bf.q = *(const u32x4*)&patch[PADDR(ptap, 2 * s + hi)];
                acc1 = __builtin_amdgcn_mfma_f32_32x32x16_f16(
                    owAv[(kk * 4 + s) * 64 + lane], bf.v, acc1, 0, 0, 0);
            }
        }
        // bias + sigmoid -> per-wave f16 LDS slice; acc1 dies here.
#pragma unroll
        for (int r = 0; r < 16; ++r) {
            int cout = (r & 3) + 8 * (r >> 2) + 4 * hi;
            if (cout < 27) {
                float a = acc1[r] + offset_b[cout];
                if (cout >= 18) a = 1.0f / (1.0f + __expf(-a));
                red[wid][cout][q] = f2h(a);
            }
        }
    }

    // ---------------- phase 2: deformable conv ----------------
    f32x16 acc[2];
#pragma unroll
    for (int m = 0; m < 2; ++m) {
#pragma unroll
        for (int r = 0; r < 16; ++r) {
            acc[m][r] = bias[m * 32 + (r & 3) + 8 * (r >> 2) + 4 * hi];
        }
    }

    for (int kk = 0; kk < 9; ++kk) {
        float dy = h2f(red[wid][2 * kk][q]);
        float dx = h2f(red[wid][2 * kk + 1][q]);
        float mm = h2f(red[wid][18 + kk][q]);

        float py = dy + (float)(kk / 3 + ho - 1);
        float px = dx + (float)(kk % 3 + wo - 1);
        float y0f = floorf(py), x0f = floorf(px);
        float wy = py - y0f, wx = px - x0f;
        int y0 = (int)y0f, x0 = (int)x0f;
        int y1 = y0 + 1, x1 = x0 + 1;
        bool y0ok = (unsigned)y0 < 128u, y1ok = (unsigned)y1 < 128u;
        bool x0ok = (unsigned)x0 < 128u, x1ok = (unsigned)x1 < 128u;
        float w0 = (y0ok && x0ok) ? (1.0f - wy) * (1.0f - wx) * mm : 0.0f;
        float w1 = (y0ok && x1ok) ? (1.0f - wy) * wx * mm : 0.0f;
        float w2 = (y1ok && x0ok) ? wy * (1.0f - wx) * mm : 0.0f;
        float w3 = (y1ok && x1ok) ? wy * wx * mm : 0.0f;
        int y0c = min(max(y0, 0), 127), y1c = min(max(y1, 0), 127);
        int x0c = min(max(x0, 0), 127), x1c = min(max(x1, 0), 127);

        f16x2 W0 = {(_Float16)w0, (_Float16)w0};
        f16x2 W1 = {(_Float16)w1, (_Float16)w1};
        f16x2 W2 = {(_Float16)w2, (_Float16)w2};
        f16x2 W3 = {(_Float16)w3, (_Float16)w3};

        int jy0 = y0c - py0, jy1 = y1c - py0;
        int jx0 = x0c - px0, jx1 = x1c - px0;
        bool inp = ((unsigned)jy0 < (unsigned)PR) && ((unsigned)jy1 < (unsigned)PR) &&
                   ((unsigned)jx0 < (unsigned)PC) && ((unsigned)jx1 < (unsigned)PC);

        // A-frags loaded just-in-time inside each step: only 2 live at once.
#define P2_STEP(S, R00, R01, R10, R11) {                                    \
            f16x8 A0 = wAv[(kk * 4 + (S)) * 64 + lane];                     \
            f16x8 A1 = wAv[(36 + kk * 4 + (S)) * 64 + lane];                \
            f16x8 bf = bilerp_frag(R00, R01, R10, R11, W0, W1, W2, W3);     \
            acc[0] = __builtin_amdgcn_mfma_f32_32x32x16_f16(A0, bf, acc[0], 0, 0, 0); \
            acc[1] = __builtin_amdgcn_mfma_f32_32x32x16_f16(A1, bf, acc[1], 0, 0, 0); \
        }

        if (__all(inp)) {
            int p00 = jy0 * PC + jx0;
            int p01 = jy0 * PC + jx1;
            int p10 = jy1 * PC + jx0;
            int p11 = jy1 * PC + jx1;
#define LRD(PX, S) (*(const u32x4*)&patch[PADDR(PX, 2 * (S) + hi)])
            P2_STEP(0, LRD(p00,0), LRD(p01,0), LRD(p10,0), LRD(p11,0));
            P2_STEP(1, LRD(p00,1), LRD(p01,1), LRD(p10,1), LRD(p11,1));
            P2_STEP(2, LRD(p00,2), LRD(p01,2), LRD(p10,2), LRD(p11,2));
            P2_STEP(3, LRD(p00,3), LRD(p01,3), LRD(p10,3), LRD(p11,3));
#undef LRD
        } else {
            int o00 = (y0c * WW + x0c) * 32 + (hi << 2);
            int o01 = (y0c * WW + x1c) * 32 + (hi << 2);
            int o10 = (y1c * WW + x0c) * 32 + (hi << 2);
            int o11 = (y1c * WW + x1c) * 32 + (hi << 2);
#define GRD(O, S) (*(const u32x4*)(xb + (O) + (S) * 8))
            P2_STEP(0, GRD(o00,0), GRD(o01,0), GRD(o10,0), GRD(o11,0));
            P2_STEP(1, GRD(o00,1), GRD(o01,1), GRD(o10,1), GRD(o11,1));
            P2_STEP(2, GRD(o00,2), GRD(o01,2), GRD(o10,2), GRD(o11,2));
            P2_STEP(3, GRD(o00,3), GRD(o01,3), GRD(o10,3), GRD(o11,3));
#undef GRD
        }
#undef P2_STEP
    }

    // D: row(cout) = m*32 + (r&3)+8*(r>>2)+4*hi, col(pixel) = q
#pragma unroll
    for (int m = 0; m < 2; ++m) {
#pragma unroll
        for (int r = 0; r < 16; ++r) {
            int cout = m * 32 + (r & 3) + 8 * (r >> 2) + 4 * hi;
            out[((size_t)b * 64 + cout) * HW + p] = acc[m][r];
        }
    }
}

// ---------------------------------------------------------------------------
extern "C" void kernel_launch(void* const* d_in, const int* in_sizes, int n_in,
                              void* d_out, int out_size, void* d_ws, size_t ws_size,
                              hipStream_t stream) {
    const float* x        = (const float*)d_in[0];
    const float* weight   = (const float*)d_in[1];
    const float* bias     = (const float*)d_in[2];
    const float* offset_w = (const float*)d_in[3];
    const float* offset_b = (const float*)d_in[4];
    float* out = (float*)d_out;

    unsigned int* xT = (unsigned int*)d_ws;                                // B*HW*32 u32 = 16MB
    unsigned short* wA  = (unsigned short*)(xT + (size_t)BATCH * HW * 32); // 4608*8
    unsigned short* owA = wA + 4608 * 8;                                   // 2304*8

    prep_kernel<<<27, 256, 0, stream>>>(weight, offset_w, wA, owA);

    int n_tiles = BATCH * HW / 64;   // 2048
    transform_kernel<<<n_tiles, 256, 0, stream>>>(x, xT);

    int n_blocks = BATCH * HW / 128; // 1024 blocks = 8 images x 128 tiles (8x16 px)
    fused_kernel<<<n_blocks, 256, 0, stream>>>(xT, wA, owA, bias, offset_b, out);
}